// Round 1
// baseline (1999.626 us; speedup 1.0000x reference)
//
#include <hip/hip_runtime.h>
#include <math.h>

#define DIM 512
#define NH 8
#define HD 64
#define SEQ 2048
#define BATCH 2
#define NLAYER 4
#define FFD 2048
#define VOCAB 32000
#define ROWS (BATCH*SEQ)   // 4096

typedef unsigned short u16;
typedef __attribute__((ext_vector_type(8))) short bfrag;   // 8 x bf16 (4 VGPRs)
typedef __attribute__((ext_vector_type(4))) float facc;    // 4 x f32

__device__ __forceinline__ u16 f2bf(float f){
  unsigned u = __builtin_bit_cast(unsigned, f);
  u += 0x7fff + ((u>>16)&1);          // RNE
  return (u16)(u>>16);
}

// ---------------- weight transpose: [batch][K][N] f32 -> [batch][N][K] bf16 ----
__global__ void transpose_w(const float* __restrict__ in, u16* __restrict__ out,
                            int K, int N){
  __shared__ float t[32][33];
  const int bz = blockIdx.z;
  const float* I = in + (size_t)bz*K*N;
  u16* O = out + (size_t)bz*K*N;
  const int n0 = blockIdx.x*32, k0 = blockIdx.y*32;
  #pragma unroll
  for (int i=0;i<4;i++){
    int k = k0 + threadIdx.y + 8*i;
    t[threadIdx.y+8*i][threadIdx.x] = I[(size_t)k*N + n0 + threadIdx.x];
  }
  __syncthreads();
  #pragma unroll
  for (int i=0;i<4;i++){
    int n = n0 + threadIdx.y + 8*i;
    O[(size_t)n*K + k0 + threadIdx.x] = f2bf(t[threadIdx.x][threadIdx.y+8*i]);
  }
}

// ---------------- embedding: h = tok_emb[x] + pos_emb ------------------------
__global__ void embed_k(const int* __restrict__ x, const float* __restrict__ tok,
                        const float* __restrict__ pos, float* __restrict__ h){
  int idx = blockIdx.x*256 + threadIdx.x;     // over ROWS*DIM/4
  int row = idx >> 7;                          // DIM/4 = 128
  int d4  = idx & 127;
  int s   = row & (SEQ-1);
  int tkn = x[row];
  float4 tv = *(const float4*)(tok + (size_t)tkn*DIM + d4*4);
  float4 pv = *(const float4*)(pos + (size_t)s*DIM + d4*4);
  float4 r; r.x=tv.x+pv.x; r.y=tv.y+pv.y; r.z=tv.z+pv.z; r.w=tv.w+pv.w;
  *(float4*)(h + (size_t)row*DIM + d4*4) = r;
}

// ---------------- layernorm: f32 in -> bf16 out ------------------------------
__global__ __launch_bounds__(256) void ln_k(const float* __restrict__ h,
    const float* __restrict__ w, const float* __restrict__ bsc,
    u16* __restrict__ out){
  const int wid = threadIdx.x>>6, lane = threadIdx.x&63;
  const int row = blockIdx.x*4 + wid;
  const float* r = h + (size_t)row*DIM + lane*8;
  float4 v0 = *(const float4*)r;
  float4 v1 = *(const float4*)(r+4);
  float s  = v0.x+v0.y+v0.z+v0.w + v1.x+v1.y+v1.z+v1.w;
  float ss = v0.x*v0.x+v0.y*v0.y+v0.z*v0.z+v0.w*v0.w
           + v1.x*v1.x+v1.y*v1.y+v1.z*v1.z+v1.w*v1.w;
  #pragma unroll
  for (int m=1;m<64;m<<=1){ s += __shfl_xor(s,m); ss += __shfl_xor(ss,m); }
  const float mean = s*(1.f/DIM);
  const float var  = ss*(1.f/DIM) - mean*mean;
  const float rsd  = rsqrtf(var + 1e-5f);
  float4 w0 = *(const float4*)(w + lane*8);
  float4 w1 = *(const float4*)(w + lane*8 + 4);
  float4 b0 = *(const float4*)(bsc + lane*8);
  float4 b1 = *(const float4*)(bsc + lane*8 + 4);
  bfrag pk;
  pk[0]=(short)f2bf((v0.x-mean)*rsd*w0.x+b0.x);
  pk[1]=(short)f2bf((v0.y-mean)*rsd*w0.y+b0.y);
  pk[2]=(short)f2bf((v0.z-mean)*rsd*w0.z+b0.z);
  pk[3]=(short)f2bf((v0.w-mean)*rsd*w0.w+b0.w);
  pk[4]=(short)f2bf((v1.x-mean)*rsd*w1.x+b1.x);
  pk[5]=(short)f2bf((v1.y-mean)*rsd*w1.y+b1.y);
  pk[6]=(short)f2bf((v1.z-mean)*rsd*w1.z+b1.z);
  pk[7]=(short)f2bf((v1.w-mean)*rsd*w1.w+b1.w);
  *(bfrag*)&out[(size_t)row*DIM + lane*8] = pk;
}

// ---------------- GEMM: C[M,N] = A[M,K](bf16) * BT[N,K]^T + bias -------------
// mode 0: Cf = v (f32)   1: Cb = bf16(v)   2: Cf += v (residual)
// mode 3: Cb = bf16(gelu_exact(v))
__global__ __launch_bounds__(256) void gemm_bt(
    const u16* __restrict__ A, const u16* __restrict__ BT,
    const float* __restrict__ bias,
    float* __restrict__ Cf, u16* __restrict__ Cb,
    int M, int N, int K, int mode){
  __shared__ __align__(16) u16 lds_a[128*32];
  __shared__ __align__(16) u16 lds_b[128*32];
  const int tid = threadIdx.x;
  const int wid = tid>>6, lane = tid&63;
  const int wr = wid>>1, wc = wid&1;
  const int lr = lane&15, lg = lane>>4;
  const int tm = blockIdx.x, tn = blockIdx.y;
  facc acc[4][4];
  #pragma unroll
  for (int i=0;i<4;i++)
    #pragma unroll
    for (int j=0;j<4;j++) acc[i][j] = (facc){0.f,0.f,0.f,0.f};
  for (int k0=0;k0<K;k0+=32){
    #pragma unroll
    for (int i=0;i<2;i++){
      int c = i*256 + tid;                 // 512 chunks of 16B
      int row = c>>2, kc = (c&3)<<3;
      *(uint4*)&lds_a[row*32+kc] = *(const uint4*)&A [(size_t)(tm*128+row)*K + k0 + kc];
      *(uint4*)&lds_b[row*32+kc] = *(const uint4*)&BT[(size_t)(tn*128+row)*K + k0 + kc];
    }
    __syncthreads();
    bfrag af[4], bf[4];
    #pragma unroll
    for (int i=0;i<4;i++) af[i] = *(const bfrag*)&lds_a[(wr*64 + i*16 + lr)*32 + lg*8];
    #pragma unroll
    for (int j=0;j<4;j++) bf[j] = *(const bfrag*)&lds_b[(wc*64 + j*16 + lr)*32 + lg*8];
    #pragma unroll
    for (int i=0;i<4;i++)
      #pragma unroll
      for (int j=0;j<4;j++)
        acc[i][j] = __builtin_amdgcn_mfma_f32_16x16x32_bf16(af[i], bf[j], acc[i][j], 0,0,0);
    __syncthreads();
  }
  #pragma unroll
  for (int i=0;i<4;i++){
    #pragma unroll
    for (int j=0;j<4;j++){
      const int col = tn*128 + wc*64 + j*16 + lr;
      const float bv = bias ? bias[col] : 0.f;
      #pragma unroll
      for (int r=0;r<4;r++){
        const int row = tm*128 + wr*64 + i*16 + lg*4 + r;
        float v = acc[i][j][r] + bv;
        const size_t o = (size_t)row*N + col;
        if      (mode==0) Cf[o] = v;
        else if (mode==1) Cb[o] = f2bf(v);
        else if (mode==2) Cf[o] += v;
        else { float g = 0.5f*v*(1.f+erff(v*0.70710678118f)); Cb[o] = f2bf(g); }
      }
    }
  }
}

// ---------------- V transpose: [B,S,D] slice head -> VT[B*H, HD, S] ----------
__global__ void vtrans_k(const u16* __restrict__ v, u16* __restrict__ vt){
  __shared__ u16 t[32][33];
  const int bz = blockIdx.z;                // b*NH + h
  const int b = bz / NH, hh = bz % NH;
  const int s0 = blockIdx.x*32, d0 = blockIdx.y*32;
  #pragma unroll
  for (int i=0;i<4;i++){
    int s = s0 + threadIdx.y + 8*i;
    t[threadIdx.y+8*i][threadIdx.x] = v[(size_t)(b*SEQ + s)*DIM + hh*HD + d0 + threadIdx.x];
  }
  __syncthreads();
  #pragma unroll
  for (int i=0;i<4;i++){
    int d = d0 + threadIdx.y + 8*i;
    vt[((size_t)bz*HD + d)*SEQ + s0 + threadIdx.x] = t[threadIdx.x][threadIdx.y+8*i];
  }
}

// ---------------- fused causal attention with phase modulation ---------------
__global__ __launch_bounds__(256) void attn_k(
    const u16* __restrict__ Q, const u16* __restrict__ Kb, const u16* __restrict__ VT,
    const float* __restrict__ qphase, u16* __restrict__ O){
  __shared__ __align__(16) u16 lds_p[4][16*32];
  const int qblk = blockIdx.x, hh = blockIdx.y, b = blockIdx.z;
  const int tid = threadIdx.x;
  const int wid = tid>>6, lane = tid&63;
  const int lr = lane&15, lg = lane>>4;
  const int qbase = qblk*64 + wid*16;
  const float ph = qphase[hh];
  const float scale = 0.125f;               // 1/sqrt(64)
  u16* pbuf = lds_p[wid];

  bfrag aq[2];
  #pragma unroll
  for (int st=0; st<2; st++)
    aq[st] = *(const bfrag*)&Q[(size_t)(b*SEQ + qbase + lr)*DIM + hh*HD + st*32 + lg*8];

  facc oacc[4];
  #pragma unroll
  for (int n=0;n<4;n++) oacc[n] = (facc){0.f,0.f,0.f,0.f};
  float mrow[4] = {-1e30f,-1e30f,-1e30f,-1e30f};
  float lrow[4] = {0.f,0.f,0.f,0.f};

  const int nkv = (qbase + 15)/32 + 1;
  for (int kt=0; kt<nkv; kt++){
    const int kv0 = kt*32;
    facc sc[2];
    #pragma unroll
    for (int j=0;j<2;j++){
      bfrag bk0 = *(const bfrag*)&Kb[(size_t)(b*SEQ + kv0 + j*16 + lr)*DIM + hh*HD + lg*8];
      bfrag bk1 = *(const bfrag*)&Kb[(size_t)(b*SEQ + kv0 + j*16 + lr)*DIM + hh*HD + 32 + lg*8];
      facc z = (facc){0.f,0.f,0.f,0.f};
      z     = __builtin_amdgcn_mfma_f32_16x16x32_bf16(aq[0], bk0, z, 0,0,0);
      sc[j] = __builtin_amdgcn_mfma_f32_16x16x32_bf16(aq[1], bk1, z, 0,0,0);
    }
    bfrag vbf[4];
    #pragma unroll
    for (int n=0;n<4;n++)
      vbf[n] = *(const bfrag*)&VT[((size_t)((b*NH + hh)*HD + n*16 + lr))*SEQ + kv0 + lg*8];

    float pv[2][4];
    float tmax[4] = {-1e30f,-1e30f,-1e30f,-1e30f};
    #pragma unroll
    for (int j=0;j<2;j++)
      #pragma unroll
      for (int r=0;r<4;r++){
        int srow = qbase + lg*4 + r;
        int scol = kv0 + j*16 + lr;
        float xv = sc[j][r]*scale;
        xv = xv*(1.f + 0.1f*cosf(ph*xv));
        if (scol > srow) xv = -1e30f;
        pv[j][r] = xv;
        tmax[r] = fmaxf(tmax[r], xv);
      }
    #pragma unroll
    for (int r=0;r<4;r++){
      float t = tmax[r];
      t = fmaxf(t, __shfl_xor(t,1));
      t = fmaxf(t, __shfl_xor(t,2));
      t = fmaxf(t, __shfl_xor(t,4));
      t = fmaxf(t, __shfl_xor(t,8));
      float mnew = fmaxf(mrow[r], t);
      float corr = expf(mrow[r] - mnew);
      float p0 = expf(pv[0][r] - mnew);
      float p1 = expf(pv[1][r] - mnew);
      pv[0][r] = p0; pv[1][r] = p1;
      float rs = p0 + p1;
      rs += __shfl_xor(rs,1);
      rs += __shfl_xor(rs,2);
      rs += __shfl_xor(rs,4);
      rs += __shfl_xor(rs,8);
      lrow[r] = lrow[r]*corr + rs;
      mrow[r] = mnew;
      #pragma unroll
      for (int n=0;n<4;n++) oacc[n][r] *= corr;
    }
    #pragma unroll
    for (int j=0;j<2;j++)
      #pragma unroll
      for (int r=0;r<4;r++)
        pbuf[(lg*4+r)*32 + j*16 + lr] = f2bf(pv[j][r]);
    bfrag pa = *(const bfrag*)&pbuf[lr*32 + lg*8];
    #pragma unroll
    for (int n=0;n<4;n++)
      oacc[n] = __builtin_amdgcn_mfma_f32_16x16x32_bf16(pa, vbf[n], oacc[n], 0,0,0);
  }
  #pragma unroll
  for (int n=0;n<4;n++)
    #pragma unroll
    for (int r=0;r<4;r++){
      float val = oacc[n][r] / lrow[r];
      O[(size_t)(b*SEQ + qbase + lg*4 + r)*DIM + hh*HD + n*16 + lr] = f2bf(val);
    }
}

// ---------------- elementwise ------------------------------------------------
__global__ void superpos_k(float* __restrict__ h, const float* __restrict__ sp){
  int idx = blockIdx.x*256 + threadIdx.x;   // ROWS*DIM/4
  int d4 = idx & 127;
  float4 hv = *(const float4*)(h + (size_t)idx*4);
  float4 pv = *(const float4*)(sp + d4*4);
  hv.x = hv.x*cosf(pv.x*hv.x);
  hv.y = hv.y*cosf(pv.y*hv.y);
  hv.z = hv.z*cosf(pv.z*hv.z);
  hv.w = hv.w*cosf(pv.w*hv.w);
  *(float4*)(h + (size_t)idx*4) = hv;
}

__global__ void tobf_k(const float* __restrict__ in, u16* __restrict__ out){
  int idx = blockIdx.x*256 + threadIdx.x;   // ROWS*DIM/8
  float4 a = *(const float4*)(in + (size_t)idx*8);
  float4 b = *(const float4*)(in + (size_t)idx*8 + 4);
  bfrag pk;
  pk[0]=(short)f2bf(a.x); pk[1]=(short)f2bf(a.y);
  pk[2]=(short)f2bf(a.z); pk[3]=(short)f2bf(a.w);
  pk[4]=(short)f2bf(b.x); pk[5]=(short)f2bf(b.y);
  pk[6]=(short)f2bf(b.z); pk[7]=(short)f2bf(b.w);
  *(bfrag*)&out[(size_t)idx*8] = pk;
}

__global__ void gate_k(float* __restrict__ h, const float* __restrict__ ir,
                       const float* __restrict__ gr){
  int idx = blockIdx.x*256 + threadIdx.x;   // ROWS*DIM/4
  float4 hv = *(const float4*)(h  + (size_t)idx*4);
  float4 iv = *(const float4*)(ir + (size_t)idx*4);
  float4 gv = *(const float4*)(gr + (size_t)idx*4);
  float g;
  g = 1.f/(1.f+expf(-gv.x)); hv.x = iv.x*g + hv.x*(1.f-g);
  g = 1.f/(1.f+expf(-gv.y)); hv.y = iv.y*g + hv.y*(1.f-g);
  g = 1.f/(1.f+expf(-gv.z)); hv.z = iv.z*g + hv.z*(1.f-g);
  g = 1.f/(1.f+expf(-gv.w)); hv.w = iv.w*g + hv.w*(1.f-g);
  *(float4*)(h + (size_t)idx*4) = hv;
}

// ---------------- host -------------------------------------------------------
extern "C" void kernel_launch(void* const* d_in, const int* in_sizes, int n_in,
                              void* d_out, int out_size, void* d_ws, size_t ws_size,
                              hipStream_t stream){
  const int*   x        = (const int*)d_in[0];
  const float* tok_emb  = (const float*)d_in[1];
  const float* pos_emb  = (const float*)d_in[2];
  const float* qw = (const float*)d_in[3];  const float* qb = (const float*)d_in[4];
  const float* kw = (const float*)d_in[5];  const float* kb = (const float*)d_in[6];
  const float* vw = (const float*)d_in[7];  const float* vb = (const float*)d_in[8];
  const float* ow = (const float*)d_in[9];  const float* ob = (const float*)d_in[10];
  const float* qphase   = (const float*)d_in[11];
  const float* sp_phase = (const float*)d_in[12];
  const float* n1w = (const float*)d_in[13]; const float* n1b = (const float*)d_in[14];
  const float* n2w = (const float*)d_in[15]; const float* n2b = (const float*)d_in[16];
  const float* f1w = (const float*)d_in[17]; const float* f1b = (const float*)d_in[18];
  const float* f2w = (const float*)d_in[19]; const float* f2b = (const float*)d_in[20];
  const float* iw  = (const float*)d_in[21]; const float* ib  = (const float*)d_in[22];
  const float* gw  = (const float*)d_in[23]; const float* gb  = (const float*)d_in[24];
  const float* nw  = (const float*)d_in[25]; const float* nb  = (const float*)d_in[26];
  const float* outw= (const float*)d_in[27]; const float* outb= (const float*)d_in[28];
  float* out = (float*)d_out;

  char* base = (char*)d_ws;
  size_t off = 0;
  auto alloc = [&](size_t bytes)->void*{
    void* p = base + off; off += bytes; off = (off + 255) & ~(size_t)255; return p;
  };
  float* h    = (float*)alloc((size_t)ROWS*DIM*4);
  u16* hn     = (u16*)alloc((size_t)ROWS*DIM*2);
  u16* qB     = (u16*)alloc((size_t)ROWS*DIM*2);
  u16* kB     = (u16*)alloc((size_t)ROWS*DIM*2);
  u16* vB     = (u16*)alloc((size_t)ROWS*DIM*2);
  u16* vTb    = (u16*)alloc((size_t)ROWS*DIM*2);
  u16* oB     = (u16*)alloc((size_t)ROWS*DIM*2);
  u16* hB     = (u16*)alloc((size_t)ROWS*DIM*2);
  u16* ffB    = (u16*)alloc((size_t)ROWS*FFD*2);
  float* iraw = (float*)alloc((size_t)ROWS*DIM*4);
  float* graw = (float*)alloc((size_t)ROWS*DIM*4);
  u16* qwT = (u16*)alloc((size_t)NLAYER*DIM*DIM*2);
  u16* kwT = (u16*)alloc((size_t)NLAYER*DIM*DIM*2);
  u16* vwT = (u16*)alloc((size_t)NLAYER*DIM*DIM*2);
  u16* owT = (u16*)alloc((size_t)NLAYER*DIM*DIM*2);
  u16* iwT = (u16*)alloc((size_t)NLAYER*DIM*DIM*2);
  u16* gwT = (u16*)alloc((size_t)NLAYER*DIM*DIM*2);
  u16* f1T = (u16*)alloc((size_t)NLAYER*DIM*FFD*2);
  u16* f2T = (u16*)alloc((size_t)NLAYER*DIM*FFD*2);
  u16* outT= (u16*)alloc((size_t)VOCAB*DIM*2);

  dim3 tb(32,8);
  transpose_w<<<dim3(DIM/32, DIM/32, NLAYER), tb, 0, stream>>>(qw, qwT, DIM, DIM);
  transpose_w<<<dim3(DIM/32, DIM/32, NLAYER), tb, 0, stream>>>(kw, kwT, DIM, DIM);
  transpose_w<<<dim3(DIM/32, DIM/32, NLAYER), tb, 0, stream>>>(vw, vwT, DIM, DIM);
  transpose_w<<<dim3(DIM/32, DIM/32, NLAYER), tb, 0, stream>>>(ow, owT, DIM, DIM);
  transpose_w<<<dim3(DIM/32, DIM/32, NLAYER), tb, 0, stream>>>(iw, iwT, DIM, DIM);
  transpose_w<<<dim3(DIM/32, DIM/32, NLAYER), tb, 0, stream>>>(gw, gwT, DIM, DIM);
  transpose_w<<<dim3(FFD/32, DIM/32, NLAYER), tb, 0, stream>>>(f1w, f1T, DIM, FFD);
  transpose_w<<<dim3(DIM/32, FFD/32, NLAYER), tb, 0, stream>>>(f2w, f2T, FFD, DIM);
  transpose_w<<<dim3(VOCAB/32, DIM/32, 1),    tb, 0, stream>>>(outw, outT, DIM, VOCAB);

  embed_k<<<ROWS*DIM/4/256, 256, 0, stream>>>(x, tok_emb, pos_emb, h);

  auto gemm = [&](const u16* A, const u16* BT, const float* bias,
                  float* Cf, u16* Cb, int M, int N, int K, int mode){
    gemm_bt<<<dim3(M/128, N/128), 256, 0, stream>>>(A, BT, bias, Cf, Cb, M, N, K, mode);
  };

  for (int l=0;l<NLAYER;l++){
    ln_k<<<ROWS/4, 256, 0, stream>>>(h, n1w + l*DIM, n1b + l*DIM, hn);
    gemm(hn, qwT + (size_t)l*DIM*DIM, qb + l*DIM, nullptr, qB, ROWS, DIM, DIM, 1);
    gemm(hn, kwT + (size_t)l*DIM*DIM, kb + l*DIM, nullptr, kB, ROWS, DIM, DIM, 1);
    gemm(hn, vwT + (size_t)l*DIM*DIM, vb + l*DIM, nullptr, vB, ROWS, DIM, DIM, 1);
    vtrans_k<<<dim3(SEQ/32, HD/32, BATCH*NH), tb, 0, stream>>>(vB, vTb);
    attn_k<<<dim3(SEQ/64, NH, BATCH), 256, 0, stream>>>(qB, kB, vTb, qphase + l*NH, oB);
    gemm(oB, owT + (size_t)l*DIM*DIM, ob + l*DIM, h, nullptr, ROWS, DIM, DIM, 2);
    superpos_k<<<ROWS*DIM/4/256, 256, 0, stream>>>(h, sp_phase + l*DIM);
    ln_k<<<ROWS/4, 256, 0, stream>>>(h, n2w + l*DIM, n2b + l*DIM, hn);
    gemm(hn, f1T + (size_t)l*DIM*FFD, f1b + l*FFD, nullptr, ffB, ROWS, FFD, DIM, 3);
    gemm(ffB, f2T + (size_t)l*DIM*FFD, f2b + l*DIM, h, nullptr, ROWS, DIM, FFD, 2);
    tobf_k<<<ROWS*DIM/8/256, 256, 0, stream>>>(h, hB);
    gemm(hB, iwT + (size_t)l*DIM*DIM, ib + l*DIM, iraw, nullptr, ROWS, DIM, DIM, 0);
    gemm(hB, gwT + (size_t)l*DIM*DIM, gb + l*DIM, graw, nullptr, ROWS, DIM, DIM, 0);
    gate_k<<<ROWS*DIM/4/256, 256, 0, stream>>>(h, iraw, graw);
  }
  ln_k<<<ROWS/4, 256, 0, stream>>>(h, nw, nb, hn);
  gemm(hn, outT, outb, out, nullptr, ROWS, VOCAB, DIM, 0);
}

// Round 2
// 1697.280 us; speedup vs baseline: 1.1781x; 1.1781x over previous
//
#include <hip/hip_runtime.h>
#include <math.h>

#define DIM 512
#define NH 8
#define HD 64
#define SEQ 2048
#define BATCH 2
#define NLAYER 4
#define FFD 2048
#define VOCAB 32000
#define ROWS (BATCH*SEQ)   // 4096
#define QKV_LD 1536

typedef unsigned short u16;
typedef __attribute__((ext_vector_type(8))) short bfrag;   // 8 x bf16 (4 VGPRs)
typedef __attribute__((ext_vector_type(4))) float facc;    // 4 x f32

__device__ __forceinline__ u16 f2bf(float f){
  unsigned u = __builtin_bit_cast(unsigned, f);
  u += 0x7fff + ((u>>16)&1);          // RNE
  return (u16)(u>>16);
}

typedef __attribute__((address_space(3))) unsigned int lds_u32;
typedef const __attribute__((address_space(1))) unsigned int glob_u32;
__device__ __forceinline__ void gload16(const void* g, void* l){
  __builtin_amdgcn_global_load_lds((glob_u32*)g, (lds_u32*)l, 16, 0, 0);
}

// ---------------- weight transpose: [z][K][N] f32 -> out[z*zStride + (nOff+n)*K + k] bf16
__global__ void transpose_w(const float* __restrict__ in, u16* __restrict__ out,
                            int K, int N, size_t zStride, int nOff){
  __shared__ float t[32][33];
  const int bz = blockIdx.z;
  const float* I = in + (size_t)bz*K*N;
  u16* O = out + (size_t)bz*zStride + (size_t)nOff*K;
  const int n0 = blockIdx.x*32, k0 = blockIdx.y*32;
  #pragma unroll
  for (int i=0;i<4;i++){
    int k = k0 + threadIdx.y + 8*i;
    t[threadIdx.y+8*i][threadIdx.x] = I[(size_t)k*N + n0 + threadIdx.x];
  }
  __syncthreads();
  #pragma unroll
  for (int i=0;i<4;i++){
    int n = n0 + threadIdx.y + 8*i;
    O[(size_t)n*K + k0 + threadIdx.x] = f2bf(t[threadIdx.x][threadIdx.y+8*i]);
  }
}

__global__ void concat3_k(const float* __restrict__ a, const float* __restrict__ b,
                          const float* __restrict__ c, float* __restrict__ o){
  int idx = blockIdx.x*256 + threadIdx.x;        // NLAYER*1536
  int l = idx/1536, r = idx%1536;
  float v = (r<512) ? a[l*512+r] : (r<1024 ? b[l*512+r-512] : c[l*512+r-1024]);
  o[idx] = v;
}
__global__ void concat2_k(const float* __restrict__ a, const float* __restrict__ b,
                          float* __restrict__ o){
  int idx = blockIdx.x*256 + threadIdx.x;        // NLAYER*1024
  int l = idx>>10, r = idx&1023;
  o[idx] = (r<512) ? a[l*512+r] : b[l*512+r-512];
}

// ---------------- embedding ---------------------------------------------------
__global__ void embed_k(const int* __restrict__ x, const float* __restrict__ tok,
                        const float* __restrict__ pos, float* __restrict__ h){
  int idx = blockIdx.x*256 + threadIdx.x;     // over ROWS*DIM/4
  int row = idx >> 7;
  int d4  = idx & 127;
  int s   = row & (SEQ-1);
  int tkn = x[row];
  float4 tv = *(const float4*)(tok + (size_t)tkn*DIM + d4*4);
  float4 pv = *(const float4*)(pos + (size_t)s*DIM + d4*4);
  float4 r; r.x=tv.x+pv.x; r.y=tv.y+pv.y; r.z=tv.z+pv.z; r.w=tv.w+pv.w;
  *(float4*)(h + (size_t)row*DIM + d4*4) = r;
}

// ---------------- layernorm: f32 in -> bf16 out ------------------------------
__global__ __launch_bounds__(256) void ln_k(const float* __restrict__ h,
    const float* __restrict__ w, const float* __restrict__ bsc,
    u16* __restrict__ out){
  const int wid = threadIdx.x>>6, lane = threadIdx.x&63;
  const int row = blockIdx.x*4 + wid;
  const float* r = h + (size_t)row*DIM + lane*8;
  float4 v0 = *(const float4*)r;
  float4 v1 = *(const float4*)(r+4);
  float s  = v0.x+v0.y+v0.z+v0.w + v1.x+v1.y+v1.z+v1.w;
  float ss = v0.x*v0.x+v0.y*v0.y+v0.z*v0.z+v0.w*v0.w
           + v1.x*v1.x+v1.y*v1.y+v1.z*v1.z+v1.w*v1.w;
  #pragma unroll
  for (int m=1;m<64;m<<=1){ s += __shfl_xor(s,m); ss += __shfl_xor(ss,m); }
  const float mean = s*(1.f/DIM);
  const float var  = ss*(1.f/DIM) - mean*mean;
  const float rsd  = rsqrtf(var + 1e-5f);
  float4 w0 = *(const float4*)(w + lane*8);
  float4 w1 = *(const float4*)(w + lane*8 + 4);
  float4 b0 = *(const float4*)(bsc + lane*8);
  float4 b1 = *(const float4*)(bsc + lane*8 + 4);
  bfrag pk;
  pk[0]=(short)f2bf((v0.x-mean)*rsd*w0.x+b0.x);
  pk[1]=(short)f2bf((v0.y-mean)*rsd*w0.y+b0.y);
  pk[2]=(short)f2bf((v0.z-mean)*rsd*w0.z+b0.z);
  pk[3]=(short)f2bf((v0.w-mean)*rsd*w0.w+b0.w);
  pk[4]=(short)f2bf((v1.x-mean)*rsd*w1.x+b1.x);
  pk[5]=(short)f2bf((v1.y-mean)*rsd*w1.y+b1.y);
  pk[6]=(short)f2bf((v1.z-mean)*rsd*w1.z+b1.z);
  pk[7]=(short)f2bf((v1.w-mean)*rsd*w1.w+b1.w);
  *(bfrag*)&out[(size_t)row*DIM + lane*8] = pk;
}

// ---------------- GEMM: C[M,N] = A[M,K](bf16) * BT[N,K]^T + bias -------------
// MODE 0: Cf = v     1: Cb = bf16(v)     3: Cb = bf16(gelu(v))
// MODE 4: t = Cf+v; t *= cos(aux[col]*t); Cf = t          (residual+superpos)
// MODE 6: t = Cf+v; Cf = t; Cb = bf16(t)                  (residual + tobf)
template<int FI, int FJ, int WRN, int WCN, int MODE>
__global__ __launch_bounds__(256) void gemm_bt(
    const u16* __restrict__ A, const u16* __restrict__ BT,
    const float* __restrict__ bias, const float* __restrict__ aux,
    float* __restrict__ Cf, u16* __restrict__ Cb,
    int M, int N, int K){
  constexpr int BM = FI*16*WRN;
  constexpr int BN = FJ*16*WCN;
  __shared__ __align__(16) u16 lds_a[BM*32];
  __shared__ __align__(16) u16 lds_b[BN*32];
  const int tid = threadIdx.x;
  const int wid = tid>>6, lane = tid&63;
  const int wr = wid / WCN, wc = wid % WCN;
  const int lr = lane&15, lg = lane>>4;
  // bijective XCD swizzle (all our grids are %8 == 0)
  const unsigned nwg = gridDim.x*gridDim.y;
  const unsigned lin = blockIdx.y*gridDim.x + blockIdx.x;
  const unsigned q = nwg >> 3;
  const unsigned sw = (lin & 7)*q + (lin >> 3);
  const int tm = sw % gridDim.x, tn = sw / gridDim.x;

  facc acc[FI][FJ];
  #pragma unroll
  for (int i=0;i<FI;i++)
    #pragma unroll
    for (int j=0;j<FJ;j++) acc[i][j] = (facc){0.f,0.f,0.f,0.f};

  for (int k0=0;k0<K;k0+=32){
    #pragma unroll
    for (int u0=0; u0<BM*4; u0+=256){
      int u = u0 + tid;
      int row = u>>2, c = (u&3) ^ ((row>>1)&3);
      gload16(&A[(size_t)(tm*BM+row)*K + k0 + c*8], &lds_a[u*8]);
    }
    #pragma unroll
    for (int u0=0; u0<BN*4; u0+=256){
      int u = u0 + tid;
      int row = u>>2, c = (u&3) ^ ((row>>1)&3);
      gload16(&BT[(size_t)(tn*BN+row)*K + k0 + c*8], &lds_b[u*8]);
    }
    __syncthreads();
    bfrag af[FI], bf[FJ];
    #pragma unroll
    for (int i=0;i<FI;i++){
      int row = wr*(FI*16) + i*16 + lr;
      af[i] = *(const bfrag*)&lds_a[row*32 + ((lg ^ ((row>>1)&3))*8)];
    }
    #pragma unroll
    for (int j=0;j<FJ;j++){
      int row = wc*(FJ*16) + j*16 + lr;
      bf[j] = *(const bfrag*)&lds_b[row*32 + ((lg ^ ((row>>1)&3))*8)];
    }
    #pragma unroll
    for (int i=0;i<FI;i++)
      #pragma unroll
      for (int j=0;j<FJ;j++)
        acc[i][j] = __builtin_amdgcn_mfma_f32_16x16x32_bf16(af[i], bf[j], acc[i][j], 0,0,0);
    __syncthreads();
  }
  #pragma unroll
  for (int i=0;i<FI;i++){
    #pragma unroll
    for (int j=0;j<FJ;j++){
      const int col = tn*BN + wc*(FJ*16) + j*16 + lr;
      const float bv = bias ? bias[col] : 0.f;
      #pragma unroll
      for (int r=0;r<4;r++){
        const int row = tm*BM + wr*(FI*16) + i*16 + lg*4 + r;
        float v = acc[i][j][r] + bv;
        const size_t o = (size_t)row*N + col;
        if      (MODE==0) Cf[o] = v;
        else if (MODE==1) Cb[o] = f2bf(v);
        else if (MODE==3){ float g = 0.5f*v*(1.f+erff(v*0.70710678118f)); Cb[o] = f2bf(g); }
        else if (MODE==4){ float t = Cf[o] + v; t = t*cosf(aux[col]*t); Cf[o] = t; }
        else if (MODE==6){ float t = Cf[o] + v; Cf[o] = t; Cb[o] = f2bf(t); }
      }
    }
  }
}

// ---------------- V transpose: qkv[.,1024+ h*HD + d] -> VT[B*H, HD, S] -------
__global__ void vtrans_k(const u16* __restrict__ v, u16* __restrict__ vt){
  __shared__ u16 t[32][33];
  const int bz = blockIdx.z;                // b*NH + h
  const int b = bz / NH, hh = bz % NH;
  const int s0 = blockIdx.x*32, d0 = blockIdx.y*32;
  #pragma unroll
  for (int i=0;i<4;i++){
    int s = s0 + threadIdx.y + 8*i;
    t[threadIdx.y+8*i][threadIdx.x] = v[(size_t)(b*SEQ + s)*QKV_LD + 1024 + hh*HD + d0 + threadIdx.x];
  }
  __syncthreads();
  #pragma unroll
  for (int i=0;i<4;i++){
    int d = d0 + threadIdx.y + 8*i;
    vt[((size_t)bz*HD + d)*SEQ + s0 + threadIdx.x] = t[threadIdx.x][threadIdx.y+8*i];
  }
}

// ---------------- fused causal attention with phase modulation ---------------
__global__ __launch_bounds__(256) void attn_k(
    const u16* __restrict__ QKV, const u16* __restrict__ VT,
    const float* __restrict__ qphase, u16* __restrict__ O){
  __shared__ __align__(16) u16 lds_p[4][16*32];
  const int qblk = blockIdx.x, hh = blockIdx.y, b = blockIdx.z;
  const int tid = threadIdx.x;
  const int wid = tid>>6, lane = tid&63;
  const int lr = lane&15, lg = lane>>4;
  const int qbase = qblk*64 + wid*16;
  const float ph = qphase[hh];
  const float scale = 0.125f;               // 1/sqrt(64)
  u16* pbuf = lds_p[wid];

  bfrag aq[2];
  #pragma unroll
  for (int st=0; st<2; st++)
    aq[st] = *(const bfrag*)&QKV[(size_t)(b*SEQ + qbase + lr)*QKV_LD + hh*HD + st*32 + lg*8];

  facc oacc[4];
  #pragma unroll
  for (int n=0;n<4;n++) oacc[n] = (facc){0.f,0.f,0.f,0.f};
  float mrow[4] = {-1e30f,-1e30f,-1e30f,-1e30f};
  float lrow[4] = {0.f,0.f,0.f,0.f};

  const int nkv = (qbase + 15)/32 + 1;
  for (int kt=0; kt<nkv; kt++){
    const int kv0 = kt*32;
    facc sc[2];
    #pragma unroll
    for (int j=0;j<2;j++){
      bfrag bk0 = *(const bfrag*)&QKV[(size_t)(b*SEQ + kv0 + j*16 + lr)*QKV_LD + 512 + hh*HD + lg*8];
      bfrag bk1 = *(const bfrag*)&QKV[(size_t)(b*SEQ + kv0 + j*16 + lr)*QKV_LD + 512 + hh*HD + 32 + lg*8];
      facc z = (facc){0.f,0.f,0.f,0.f};
      z     = __builtin_amdgcn_mfma_f32_16x16x32_bf16(aq[0], bk0, z, 0,0,0);
      sc[j] = __builtin_amdgcn_mfma_f32_16x16x32_bf16(aq[1], bk1, z, 0,0,0);
    }
    bfrag vbf[4];
    #pragma unroll
    for (int n=0;n<4;n++)
      vbf[n] = *(const bfrag*)&VT[((size_t)((b*NH + hh)*HD + n*16 + lr))*SEQ + kv0 + lg*8];

    float pv[2][4];
    float tmax[4] = {-1e30f,-1e30f,-1e30f,-1e30f};
    #pragma unroll
    for (int j=0;j<2;j++)
      #pragma unroll
      for (int r=0;r<4;r++){
        int srow = qbase + lg*4 + r;
        int scol = kv0 + j*16 + lr;
        float xv = sc[j][r]*scale;
        xv = xv*(1.f + 0.1f*cosf(ph*xv));
        if (scol > srow) xv = -1e30f;
        pv[j][r] = xv;
        tmax[r] = fmaxf(tmax[r], xv);
      }
    #pragma unroll
    for (int r=0;r<4;r++){
      float t = tmax[r];
      t = fmaxf(t, __shfl_xor(t,1));
      t = fmaxf(t, __shfl_xor(t,2));
      t = fmaxf(t, __shfl_xor(t,4));
      t = fmaxf(t, __shfl_xor(t,8));
      float mnew = fmaxf(mrow[r], t);
      float corr = expf(mrow[r] - mnew);
      float p0 = expf(pv[0][r] - mnew);
      float p1 = expf(pv[1][r] - mnew);
      pv[0][r] = p0; pv[1][r] = p1;
      float rs = p0 + p1;
      rs += __shfl_xor(rs,1);
      rs += __shfl_xor(rs,2);
      rs += __shfl_xor(rs,4);
      rs += __shfl_xor(rs,8);
      lrow[r] = lrow[r]*corr + rs;
      mrow[r] = mnew;
      #pragma unroll
      for (int n=0;n<4;n++) oacc[n][r] *= corr;
    }
    #pragma unroll
    for (int j=0;j<2;j++)
      #pragma unroll
      for (int r=0;r<4;r++)
        pbuf[(lg*4+r)*32 + j*16 + lr] = f2bf(pv[j][r]);
    bfrag pa = *(const bfrag*)&pbuf[lr*32 + lg*8];
    #pragma unroll
    for (int n=0;n<4;n++)
      oacc[n] = __builtin_amdgcn_mfma_f32_16x16x32_bf16(pa, vbf[n], oacc[n], 0,0,0);
  }
  #pragma unroll
  for (int n=0;n<4;n++)
    #pragma unroll
    for (int r=0;r<4;r++){
      float val = oacc[n][r] / lrow[r];
      O[(size_t)(b*SEQ + qbase + lg*4 + r)*DIM + hh*HD + n*16 + lr] = f2bf(val);
    }
}

// ---------------- gate: h = i*g + h*(1-g) ------------------------------------
__global__ void gate_k(float* __restrict__ h, const float* __restrict__ ig){
  int idx = blockIdx.x*256 + threadIdx.x;   // ROWS*DIM/4
  int row = idx >> 7, d4 = idx & 127;
  float4 hv = *(const float4*)(h  + (size_t)idx*4);
  float4 iv = *(const float4*)(ig + (size_t)row*1024 + d4*4);
  float4 gv = *(const float4*)(ig + (size_t)row*1024 + 512 + d4*4);
  float g;
  g = 1.f/(1.f+expf(-gv.x)); hv.x = iv.x*g + hv.x*(1.f-g);
  g = 1.f/(1.f+expf(-gv.y)); hv.y = iv.y*g + hv.y*(1.f-g);
  g = 1.f/(1.f+expf(-gv.z)); hv.z = iv.z*g + hv.z*(1.f-g);
  g = 1.f/(1.f+expf(-gv.w)); hv.w = iv.w*g + hv.w*(1.f-g);
  *(float4*)(h + (size_t)idx*4) = hv;
}

// ---------------- host -------------------------------------------------------
extern "C" void kernel_launch(void* const* d_in, const int* in_sizes, int n_in,
                              void* d_out, int out_size, void* d_ws, size_t ws_size,
                              hipStream_t stream){
  const int*   x        = (const int*)d_in[0];
  const float* tok_emb  = (const float*)d_in[1];
  const float* pos_emb  = (const float*)d_in[2];
  const float* qw = (const float*)d_in[3];  const float* qb = (const float*)d_in[4];
  const float* kw = (const float*)d_in[5];  const float* kb = (const float*)d_in[6];
  const float* vw = (const float*)d_in[7];  const float* vb = (const float*)d_in[8];
  const float* ow = (const float*)d_in[9];  const float* ob = (const float*)d_in[10];
  const float* qphase   = (const float*)d_in[11];
  const float* sp_phase = (const float*)d_in[12];
  const float* n1w = (const float*)d_in[13]; const float* n1b = (const float*)d_in[14];
  const float* n2w = (const float*)d_in[15]; const float* n2b = (const float*)d_in[16];
  const float* f1w = (const float*)d_in[17]; const float* f1b = (const float*)d_in[18];
  const float* f2w = (const float*)d_in[19]; const float* f2b = (const float*)d_in[20];
  const float* iw  = (const float*)d_in[21]; const float* ib  = (const float*)d_in[22];
  const float* gw  = (const float*)d_in[23]; const float* gb  = (const float*)d_in[24];
  const float* nw  = (const float*)d_in[25]; const float* nb  = (const float*)d_in[26];
  const float* outw= (const float*)d_in[27]; const float* outb= (const float*)d_in[28];
  float* out = (float*)d_out;

  char* base = (char*)d_ws;
  size_t off = 0;
  auto alloc = [&](size_t bytes)->void*{
    void* p = base + off; off += bytes; off = (off + 255) & ~(size_t)255; return p;
  };
  float* h    = (float*)alloc((size_t)ROWS*DIM*4);
  u16* hn     = (u16*)alloc((size_t)ROWS*DIM*2);
  u16* qkvB   = (u16*)alloc((size_t)ROWS*QKV_LD*2);
  u16* vTb    = (u16*)alloc((size_t)ROWS*DIM*2);
  u16* oB     = (u16*)alloc((size_t)ROWS*DIM*2);
  u16* hB     = (u16*)alloc((size_t)ROWS*DIM*2);
  u16* ffB    = (u16*)alloc((size_t)ROWS*FFD*2);
  float* igF  = (float*)alloc((size_t)ROWS*1024*4);
  u16* qkvT = (u16*)alloc((size_t)NLAYER*1536*DIM*2);
  u16* owT  = (u16*)alloc((size_t)NLAYER*DIM*DIM*2);
  u16* igT  = (u16*)alloc((size_t)NLAYER*1024*DIM*2);
  u16* f1T  = (u16*)alloc((size_t)NLAYER*DIM*FFD*2);
  u16* f2T  = (u16*)alloc((size_t)NLAYER*DIM*FFD*2);
  u16* outT = (u16*)alloc((size_t)VOCAB*DIM*2);
  float* qkvb = (float*)alloc((size_t)NLAYER*1536*4);
  float* igb  = (float*)alloc((size_t)NLAYER*1024*4);

  dim3 tb(32,8);
  transpose_w<<<dim3(DIM/32, DIM/32, NLAYER), tb, 0, stream>>>(qw, qkvT, DIM, DIM, (size_t)1536*DIM, 0);
  transpose_w<<<dim3(DIM/32, DIM/32, NLAYER), tb, 0, stream>>>(kw, qkvT, DIM, DIM, (size_t)1536*DIM, 512);
  transpose_w<<<dim3(DIM/32, DIM/32, NLAYER), tb, 0, stream>>>(vw, qkvT, DIM, DIM, (size_t)1536*DIM, 1024);
  transpose_w<<<dim3(DIM/32, DIM/32, NLAYER), tb, 0, stream>>>(ow, owT, DIM, DIM, (size_t)DIM*DIM, 0);
  transpose_w<<<dim3(DIM/32, DIM/32, NLAYER), tb, 0, stream>>>(iw, igT, DIM, DIM, (size_t)1024*DIM, 0);
  transpose_w<<<dim3(DIM/32, DIM/32, NLAYER), tb, 0, stream>>>(gw, igT, DIM, DIM, (size_t)1024*DIM, 512);
  transpose_w<<<dim3(FFD/32, DIM/32, NLAYER), tb, 0, stream>>>(f1w, f1T, DIM, FFD, (size_t)DIM*FFD, 0);
  transpose_w<<<dim3(DIM/32, FFD/32, NLAYER), tb, 0, stream>>>(f2w, f2T, FFD, DIM, (size_t)DIM*FFD, 0);
  transpose_w<<<dim3(VOCAB/32, DIM/32, 1),    tb, 0, stream>>>(outw, outT, DIM, VOCAB, 0, 0);
  concat3_k<<<NLAYER*1536/256, 256, 0, stream>>>(qb, kb, vb, qkvb);
  concat2_k<<<NLAYER*1024/256, 256, 0, stream>>>(ib, gb, igb);

  embed_k<<<ROWS*DIM/4/256, 256, 0, stream>>>(x, tok_emb, pos_emb, h);

  for (int l=0;l<NLAYER;l++){
    ln_k<<<ROWS/4, 256, 0, stream>>>(h, n1w + l*DIM, n1b + l*DIM, hn);
    gemm_bt<4,4,2,2,1><<<dim3(ROWS/128, 1536/128), 256, 0, stream>>>(
        hn, qkvT + (size_t)l*1536*DIM, qkvb + l*1536, nullptr, nullptr, qkvB, ROWS, 1536, DIM);
    vtrans_k<<<dim3(SEQ/32, HD/32, BATCH*NH), tb, 0, stream>>>(qkvB, vTb);
    attn_k<<<dim3(SEQ/64, NH, BATCH), 256, 0, stream>>>(qkvB, vTb, qphase + l*NH, oB);
    gemm_bt<4,2,1,4,4><<<dim3(ROWS/64, DIM/128), 256, 0, stream>>>(
        oB, owT + (size_t)l*DIM*DIM, ob + l*DIM, sp_phase + l*DIM, h, nullptr, ROWS, DIM, DIM);
    ln_k<<<ROWS/4, 256, 0, stream>>>(h, n2w + l*DIM, n2b + l*DIM, hn);
    gemm_bt<4,4,2,2,3><<<dim3(ROWS/128, FFD/128), 256, 0, stream>>>(
        hn, f1T + (size_t)l*DIM*FFD, f1b + l*FFD, nullptr, nullptr, ffB, ROWS, FFD, DIM);
    gemm_bt<4,2,1,4,6><<<dim3(ROWS/64, DIM/128), 256, 0, stream>>>(
        ffB, f2T + (size_t)l*DIM*FFD, f2b + l*DIM, nullptr, h, hB, ROWS, DIM, FFD);
    gemm_bt<4,4,2,2,0><<<dim3(ROWS/128, 1024/128), 256, 0, stream>>>(
        hB, igT + (size_t)l*1024*DIM, igb + l*1024, nullptr, igF, nullptr, ROWS, 1024, DIM);
    gate_k<<<ROWS*DIM/4/256, 256, 0, stream>>>(h, igF);
  }
  ln_k<<<ROWS/4, 256, 0, stream>>>(h, nw, nb, hn);
  gemm_bt<4,4,2,2,0><<<dim3(ROWS/128, VOCAB/128), 256, 0, stream>>>(
      hn, outT, outb, nullptr, out, nullptr, ROWS, VOCAB, DIM);
}

// Round 3
// 1208.718 us; speedup vs baseline: 1.6543x; 1.4042x over previous
//
#include <hip/hip_runtime.h>
#include <math.h>

#define DIM 512
#define NH 8
#define HD 64
#define SEQ 2048
#define BATCH 2
#define NLAYER 4
#define FFD 2048
#define VOCAB 32000
#define ROWS (BATCH*SEQ)   // 4096
#define QKV_LD 1536

typedef unsigned short u16;
typedef __attribute__((ext_vector_type(8))) short bfrag;   // 8 x bf16 (4 VGPRs)
typedef __attribute__((ext_vector_type(4))) float facc;    // 4 x f32

__device__ __forceinline__ u16 f2bf(float f){
  unsigned u = __builtin_bit_cast(unsigned, f);
  u += 0x7fff + ((u>>16)&1);          // RNE
  return (u16)(u>>16);
}

typedef __attribute__((address_space(3))) unsigned int lds_u32;
typedef const __attribute__((address_space(1))) unsigned int glob_u32;
__device__ __forceinline__ void gload16(const void* g, void* l){
  __builtin_amdgcn_global_load_lds((glob_u32*)g, (lds_u32*)l, 16, 0, 0);
}

template<int N> __device__ __forceinline__ void wait_vmcnt(){
  if constexpr (N==0)      asm volatile("s_waitcnt vmcnt(0)" ::: "memory");
  else if constexpr (N==3) asm volatile("s_waitcnt vmcnt(3)" ::: "memory");
  else if constexpr (N==4) asm volatile("s_waitcnt vmcnt(4)" ::: "memory");
  else if constexpr (N==8) asm volatile("s_waitcnt vmcnt(8)" ::: "memory");
  else static_assert(N==0, "unsupported vmcnt");
}

// ---------------- weight transpose: [z][K][N] f32 -> out[z*zStride + (nOff+n)*K + k] bf16
__global__ void transpose_w(const float* __restrict__ in, u16* __restrict__ out,
                            int K, int N, size_t zStride, int nOff){
  __shared__ float t[32][33];
  const int bz = blockIdx.z;
  const float* I = in + (size_t)bz*K*N;
  u16* O = out + (size_t)bz*zStride + (size_t)nOff*K;
  const int n0 = blockIdx.x*32, k0 = blockIdx.y*32;
  #pragma unroll
  for (int i=0;i<4;i++){
    int k = k0 + threadIdx.y + 8*i;
    t[threadIdx.y+8*i][threadIdx.x] = I[(size_t)k*N + n0 + threadIdx.x];
  }
  __syncthreads();
  #pragma unroll
  for (int i=0;i<4;i++){
    int n = n0 + threadIdx.y + 8*i;
    O[(size_t)n*K + k0 + threadIdx.x] = f2bf(t[threadIdx.x][threadIdx.y+8*i]);
  }
}

__global__ void concat3_k(const float* __restrict__ a, const float* __restrict__ b,
                          const float* __restrict__ c, float* __restrict__ o){
  int idx = blockIdx.x*256 + threadIdx.x;        // NLAYER*1536
  int l = idx/1536, r = idx%1536;
  float v = (r<512) ? a[l*512+r] : (r<1024 ? b[l*512+r-512] : c[l*512+r-1024]);
  o[idx] = v;
}
__global__ void concat2_k(const float* __restrict__ a, const float* __restrict__ b,
                          float* __restrict__ o){
  int idx = blockIdx.x*256 + threadIdx.x;        // NLAYER*1024
  int l = idx>>10, r = idx&1023;
  o[idx] = (r<512) ? a[l*512+r] : b[l*512+r-512];
}

// ---------------- embedding ---------------------------------------------------
__global__ void embed_k(const int* __restrict__ x, const float* __restrict__ tok,
                        const float* __restrict__ pos, float* __restrict__ h){
  int idx = blockIdx.x*256 + threadIdx.x;     // over ROWS*DIM/4
  int row = idx >> 7;
  int d4  = idx & 127;
  int s   = row & (SEQ-1);
  int tkn = x[row];
  float4 tv = *(const float4*)(tok + (size_t)tkn*DIM + d4*4);
  float4 pv = *(const float4*)(pos + (size_t)s*DIM + d4*4);
  float4 r; r.x=tv.x+pv.x; r.y=tv.y+pv.y; r.z=tv.z+pv.z; r.w=tv.w+pv.w;
  *(float4*)(h + (size_t)row*DIM + d4*4) = r;
}

// ---------------- layernorm: f32 in -> bf16 out ------------------------------
__global__ __launch_bounds__(256) void ln_k(const float* __restrict__ h,
    const float* __restrict__ w, const float* __restrict__ bsc,
    u16* __restrict__ out){
  const int wid = threadIdx.x>>6, lane = threadIdx.x&63;
  const int row = blockIdx.x*4 + wid;
  const float* r = h + (size_t)row*DIM + lane*8;
  float4 v0 = *(const float4*)r;
  float4 v1 = *(const float4*)(r+4);
  float s  = v0.x+v0.y+v0.z+v0.w + v1.x+v1.y+v1.z+v1.w;
  float ss = v0.x*v0.x+v0.y*v0.y+v0.z*v0.z+v0.w*v0.w
           + v1.x*v1.x+v1.y*v1.y+v1.z*v1.z+v1.w*v1.w;
  #pragma unroll
  for (int m=1;m<64;m<<=1){ s += __shfl_xor(s,m); ss += __shfl_xor(ss,m); }
  const float mean = s*(1.f/DIM);
  const float var  = ss*(1.f/DIM) - mean*mean;
  const float rsd  = rsqrtf(var + 1e-5f);
  float4 w0 = *(const float4*)(w + lane*8);
  float4 w1 = *(const float4*)(w + lane*8 + 4);
  float4 b0 = *(const float4*)(bsc + lane*8);
  float4 b1 = *(const float4*)(bsc + lane*8 + 4);
  bfrag pk;
  pk[0]=(short)f2bf((v0.x-mean)*rsd*w0.x+b0.x);
  pk[1]=(short)f2bf((v0.y-mean)*rsd*w0.y+b0.y);
  pk[2]=(short)f2bf((v0.z-mean)*rsd*w0.z+b0.z);
  pk[3]=(short)f2bf((v0.w-mean)*rsd*w0.w+b0.w);
  pk[4]=(short)f2bf((v1.x-mean)*rsd*w1.x+b1.x);
  pk[5]=(short)f2bf((v1.y-mean)*rsd*w1.y+b1.y);
  pk[6]=(short)f2bf((v1.z-mean)*rsd*w1.z+b1.z);
  pk[7]=(short)f2bf((v1.w-mean)*rsd*w1.w+b1.w);
  *(bfrag*)&out[(size_t)row*DIM + lane*8] = pk;
}

// ---------------- pipelined GEMM: C[M,N] = A[M,K](bf16) * BT[N,K]^T + bias ---
// depth-2 dbuf staging via global_load_lds; counted vmcnt; raw s_barrier.
// MODE 0: Cf = v     1: Cb = bf16(v)     3: Cb = bf16(gelu(v))
// MODE 4: t = Cf+v; t *= cos(aux[col]*t); Cf = t          (residual+superpos)
// MODE 6: t = Cf+v; Cf = t; Cb = bf16(t)                  (residual + tobf)
template<int BM,int BN,int BK,int WRN,int WCN,int MODE>
__global__ __launch_bounds__(WRN*WCN*64, 2) void gemm_p(
    const u16* __restrict__ A, const u16* __restrict__ BT,
    const float* __restrict__ bias, const float* __restrict__ aux,
    float* __restrict__ Cf, u16* __restrict__ Cb,
    int M, int N, int K){
  constexpr int NTH = WRN*WCN*64;
  constexpr int FI  = BM/(16*WRN);
  constexpr int FJ  = BN/(16*WCN);
  constexpr int CPR = BK/8;              // 16B chunks per row
  constexpr int LA  = BM*CPR/NTH;
  constexpr int LB  = BN*CPR/NTH;
  constexpr int LPT = LA+LB;
  constexpr int NKK = BK/32;
  extern __shared__ __align__(16) u16 smem[];
  u16* lds_a = smem;                     // [2][BM*BK]
  u16* lds_b = smem + 2*BM*BK;           // [2][BN*BK]

  const int tid = threadIdx.x;
  const int wid = tid>>6, lane = tid&63;
  const int wr = wid / WCN, wc = wid % WCN;
  const int lr = lane&15, lg = lane>>4;
  // bijective XCD swizzle (all grids are %8 == 0)
  const unsigned nwg = gridDim.x*gridDim.y;
  const unsigned lin = blockIdx.y*gridDim.x + blockIdx.x;
  const unsigned q = nwg >> 3;
  const unsigned sw = (lin & 7)*q + (lin >> 3);
  const int tm = sw % gridDim.x, tn = sw / gridDim.x;

  auto swzf = [](int row)->int{ return (BK==64) ? (row&7) : ((row>>1)&3); };

  auto stage = [&](int t, int buf){
    const int k0 = t*BK;
    #pragma unroll
    for (int i=0;i<LA;i++){
      int u = i*NTH + tid;
      int row = u/CPR, c = (u%CPR) ^ swzf(row);
      gload16(&A[(size_t)(tm*BM+row)*K + k0 + c*8], &lds_a[buf*BM*BK + u*8]);
    }
    #pragma unroll
    for (int i=0;i<LB;i++){
      int u = i*NTH + tid;
      int row = u/CPR, c = (u%CPR) ^ swzf(row);
      gload16(&BT[(size_t)(tn*BN+row)*K + k0 + c*8], &lds_b[buf*BN*BK + u*8]);
    }
  };

  facc acc[FI][FJ] = {};
  const int NT = K/BK;
  stage(0,0); stage(1,1);
  for (int t=0;t<NT;t++){
    const int buf = t&1;
    const u16* la = &lds_a[buf*BM*BK];
    const u16* lb = &lds_b[buf*BN*BK];
    if (t<NT-1) wait_vmcnt<LPT>(); else wait_vmcnt<0>();
    __builtin_amdgcn_s_barrier();
    __builtin_amdgcn_sched_barrier(0);
    bfrag af[FI], bf[FJ];
    #pragma unroll
    for (int i=0;i<FI;i++){
      int row = wr*(FI*16) + i*16 + lr;
      af[i] = *(const bfrag*)&la[row*BK + ((lg ^ swzf(row))*8)];
    }
    #pragma unroll
    for (int j=0;j<FJ;j++){
      int row = wc*(FJ*16) + j*16 + lr;
      bf[j] = *(const bfrag*)&lb[row*BK + ((lg ^ swzf(row))*8)];
    }
    if constexpr (NKK==1){
      asm volatile("s_waitcnt lgkmcnt(0)" ::: "memory");
      __builtin_amdgcn_sched_barrier(0);
      __builtin_amdgcn_s_barrier();
      __builtin_amdgcn_sched_barrier(0);
      if (t+2<NT) stage(t+2, buf);
      __builtin_amdgcn_s_setprio(1);
      #pragma unroll
      for (int i=0;i<FI;i++)
        #pragma unroll
        for (int j=0;j<FJ;j++)
          acc[i][j] = __builtin_amdgcn_mfma_f32_16x16x32_bf16(af[i], bf[j], acc[i][j],0,0,0);
      __builtin_amdgcn_s_setprio(0);
    } else {
      // kk = 0 compute
      __builtin_amdgcn_s_setprio(1);
      #pragma unroll
      for (int i=0;i<FI;i++)
        #pragma unroll
        for (int j=0;j<FJ;j++)
          acc[i][j] = __builtin_amdgcn_mfma_f32_16x16x32_bf16(af[i], bf[j], acc[i][j],0,0,0);
      __builtin_amdgcn_s_setprio(0);
      // kk = 1 reads
      bfrag af1[FI], bf1[FJ];
      #pragma unroll
      for (int i=0;i<FI;i++){
        int row = wr*(FI*16) + i*16 + lr;
        af1[i] = *(const bfrag*)&la[row*BK + (((4+lg) ^ swzf(row))*8)];
      }
      #pragma unroll
      for (int j=0;j<FJ;j++){
        int row = wc*(FJ*16) + j*16 + lr;
        bf1[j] = *(const bfrag*)&lb[row*BK + (((4+lg) ^ swzf(row))*8)];
      }
      asm volatile("s_waitcnt lgkmcnt(0)" ::: "memory");
      __builtin_amdgcn_sched_barrier(0);
      __builtin_amdgcn_s_barrier();
      __builtin_amdgcn_sched_barrier(0);
      if (t+2<NT) stage(t+2, buf);
      __builtin_amdgcn_s_setprio(1);
      #pragma unroll
      for (int i=0;i<FI;i++)
        #pragma unroll
        for (int j=0;j<FJ;j++)
          acc[i][j] = __builtin_amdgcn_mfma_f32_16x16x32_bf16(af1[i], bf1[j], acc[i][j],0,0,0);
      __builtin_amdgcn_s_setprio(0);
    }
  }
  #pragma unroll
  for (int i=0;i<FI;i++){
    #pragma unroll
    for (int j=0;j<FJ;j++){
      const int col = tn*BN + wc*(FJ*16) + j*16 + lr;
      const float bv = bias ? bias[col] : 0.f;
      #pragma unroll
      for (int r=0;r<4;r++){
        const int row = tm*BM + wr*(FI*16) + i*16 + lg*4 + r;
        float v = acc[i][j][r] + bv;
        const size_t o = (size_t)row*N + col;
        if      (MODE==0) Cf[o] = v;
        else if (MODE==1) Cb[o] = f2bf(v);
        else if (MODE==3){ float g = 0.5f*v*(1.f+erff(v*0.70710678118f)); Cb[o] = f2bf(g); }
        else if (MODE==4){ float t = Cf[o] + v; t = t*__cosf(aux[col]*t); Cf[o] = t; }
        else if (MODE==6){ float t = Cf[o] + v; Cf[o] = t; Cb[o] = f2bf(t); }
      }
    }
  }
}

// ---------------- V transpose: qkv[.,1024+ h*HD + d] -> VT[B*H, HD, S] -------
__global__ void vtrans_k(const u16* __restrict__ v, u16* __restrict__ vt){
  __shared__ u16 t[32][33];
  const int bz = blockIdx.z;                // b*NH + h
  const int b = bz / NH, hh = bz % NH;
  const int s0 = blockIdx.x*32, d0 = blockIdx.y*32;
  #pragma unroll
  for (int i=0;i<4;i++){
    int s = s0 + threadIdx.y + 8*i;
    t[threadIdx.y+8*i][threadIdx.x] = v[(size_t)(b*SEQ + s)*QKV_LD + 1024 + hh*HD + d0 + threadIdx.x];
  }
  __syncthreads();
  #pragma unroll
  for (int i=0;i<4;i++){
    int d = d0 + threadIdx.y + 8*i;
    vt[((size_t)bz*HD + d)*SEQ + s0 + threadIdx.x] = t[threadIdx.x][threadIdx.y+8*i];
  }
}

// ---------------- fused causal attention with phase modulation ---------------
__global__ __launch_bounds__(256) void attn_k(
    const u16* __restrict__ QKV, const u16* __restrict__ VT,
    const float* __restrict__ qphase, u16* __restrict__ O){
  __shared__ __align__(16) u16 lds_p[4][16*32];
  const int qblk = blockIdx.x, hh = blockIdx.y, b = blockIdx.z;
  const int tid = threadIdx.x;
  const int wid = tid>>6, lane = tid&63;
  const int lr = lane&15, lg = lane>>4;
  const int qbase = qblk*64 + wid*16;
  const float ph = qphase[hh];
  const float scale = 0.125f;               // 1/sqrt(64)
  u16* pbuf = lds_p[wid];

  bfrag aq[2];
  #pragma unroll
  for (int st=0; st<2; st++)
    aq[st] = *(const bfrag*)&QKV[(size_t)(b*SEQ + qbase + lr)*QKV_LD + hh*HD + st*32 + lg*8];

  facc oacc[4];
  #pragma unroll
  for (int n=0;n<4;n++) oacc[n] = (facc){0.f,0.f,0.f,0.f};
  float mrow[4] = {-1e30f,-1e30f,-1e30f,-1e30f};
  float lrow[4] = {0.f,0.f,0.f,0.f};

  const int nkv = (qbase + 15)/32 + 1;
  for (int kt=0; kt<nkv; kt++){
    const int kv0 = kt*32;
    facc sc[2];
    #pragma unroll
    for (int j=0;j<2;j++){
      bfrag bk0 = *(const bfrag*)&QKV[(size_t)(b*SEQ + kv0 + j*16 + lr)*QKV_LD + 512 + hh*HD + lg*8];
      bfrag bk1 = *(const bfrag*)&QKV[(size_t)(b*SEQ + kv0 + j*16 + lr)*QKV_LD + 512 + hh*HD + 32 + lg*8];
      facc z = (facc){0.f,0.f,0.f,0.f};
      z     = __builtin_amdgcn_mfma_f32_16x16x32_bf16(aq[0], bk0, z, 0,0,0);
      sc[j] = __builtin_amdgcn_mfma_f32_16x16x32_bf16(aq[1], bk1, z, 0,0,0);
    }
    bfrag vbf[4];
    #pragma unroll
    for (int n=0;n<4;n++)
      vbf[n] = *(const bfrag*)&VT[((size_t)((b*NH + hh)*HD + n*16 + lr))*SEQ + kv0 + lg*8];

    float pv[2][4];
    float tmax[4] = {-1e30f,-1e30f,-1e30f,-1e30f};
    #pragma unroll
    for (int j=0;j<2;j++)
      #pragma unroll
      for (int r=0;r<4;r++){
        int srow = qbase + lg*4 + r;
        int scol = kv0 + j*16 + lr;
        float xv = sc[j][r]*scale;
        xv = xv*(1.f + 0.1f*__cosf(ph*xv));
        if (scol > srow) xv = -1e30f;
        pv[j][r] = xv;
        tmax[r] = fmaxf(tmax[r], xv);
      }
    #pragma unroll
    for (int r=0;r<4;r++){
      float t = tmax[r];
      t = fmaxf(t, __shfl_xor(t,1));
      t = fmaxf(t, __shfl_xor(t,2));
      t = fmaxf(t, __shfl_xor(t,4));
      t = fmaxf(t, __shfl_xor(t,8));
      float mnew = fmaxf(mrow[r], t);
      float corr = __expf(mrow[r] - mnew);
      float p0 = __expf(pv[0][r] - mnew);
      float p1 = __expf(pv[1][r] - mnew);
      pv[0][r] = p0; pv[1][r] = p1;
      float rs = p0 + p1;
      rs += __shfl_xor(rs,1);
      rs += __shfl_xor(rs,2);
      rs += __shfl_xor(rs,4);
      rs += __shfl_xor(rs,8);
      lrow[r] = lrow[r]*corr + rs;
      mrow[r] = mnew;
      #pragma unroll
      for (int n=0;n<4;n++) oacc[n][r] *= corr;
    }
    #pragma unroll
    for (int j=0;j<2;j++)
      #pragma unroll
      for (int r=0;r<4;r++)
        pbuf[(lg*4+r)*32 + j*16 + lr] = f2bf(pv[j][r]);
    bfrag pa = *(const bfrag*)&pbuf[lr*32 + lg*8];
    #pragma unroll
    for (int n=0;n<4;n++)
      oacc[n] = __builtin_amdgcn_mfma_f32_16x16x32_bf16(pa, vbf[n], oacc[n], 0,0,0);
  }
  #pragma unroll
  for (int n=0;n<4;n++)
    #pragma unroll
    for (int r=0;r<4;r++){
      float val = oacc[n][r] / lrow[r];
      O[(size_t)(b*SEQ + qbase + lg*4 + r)*DIM + hh*HD + n*16 + lr] = f2bf(val);
    }
}

// ---------------- gate: h = i*g + h*(1-g) ------------------------------------
__global__ void gate_k(float* __restrict__ h, const float* __restrict__ ig){
  int idx = blockIdx.x*256 + threadIdx.x;   // ROWS*DIM/4
  int row = idx >> 7, d4 = idx & 127;
  float4 hv = *(const float4*)(h  + (size_t)idx*4);
  float4 iv = *(const float4*)(ig + (size_t)row*1024 + d4*4);
  float4 gv = *(const float4*)(ig + (size_t)row*1024 + 512 + d4*4);
  float g;
  g = 1.f/(1.f+__expf(-gv.x)); hv.x = iv.x*g + hv.x*(1.f-g);
  g = 1.f/(1.f+__expf(-gv.y)); hv.y = iv.y*g + hv.y*(1.f-g);
  g = 1.f/(1.f+__expf(-gv.z)); hv.z = iv.z*g + hv.z*(1.f-g);
  g = 1.f/(1.f+__expf(-gv.w)); hv.w = iv.w*g + hv.w*(1.f-g);
  *(float4*)(h + (size_t)idx*4) = hv;
}

// ---------------- host -------------------------------------------------------
extern "C" void kernel_launch(void* const* d_in, const int* in_sizes, int n_in,
                              void* d_out, int out_size, void* d_ws, size_t ws_size,
                              hipStream_t stream){
  const int*   x        = (const int*)d_in[0];
  const float* tok_emb  = (const float*)d_in[1];
  const float* pos_emb  = (const float*)d_in[2];
  const float* qw = (const float*)d_in[3];  const float* qb = (const float*)d_in[4];
  const float* kw = (const float*)d_in[5];  const float* kb = (const float*)d_in[6];
  const float* vw = (const float*)d_in[7];  const float* vb = (const float*)d_in[8];
  const float* ow = (const float*)d_in[9];  const float* ob = (const float*)d_in[10];
  const float* qphase   = (const float*)d_in[11];
  const float* sp_phase = (const float*)d_in[12];
  const float* n1w = (const float*)d_in[13]; const float* n1b = (const float*)d_in[14];
  const float* n2w = (const float*)d_in[15]; const float* n2b = (const float*)d_in[16];
  const float* f1w = (const float*)d_in[17]; const float* f1b = (const float*)d_in[18];
  const float* f2w = (const float*)d_in[19]; const float* f2b = (const float*)d_in[20];
  const float* iw  = (const float*)d_in[21]; const float* ib  = (const float*)d_in[22];
  const float* gw  = (const float*)d_in[23]; const float* gb  = (const float*)d_in[24];
  const float* nw  = (const float*)d_in[25]; const float* nb  = (const float*)d_in[26];
  const float* outw= (const float*)d_in[27]; const float* outb= (const float*)d_in[28];
  float* out = (float*)d_out;

  char* base = (char*)d_ws;
  size_t off = 0;
  auto alloc = [&](size_t bytes)->void*{
    void* p = base + off; off += bytes; off = (off + 255) & ~(size_t)255; return p;
  };
  float* h    = (float*)alloc((size_t)ROWS*DIM*4);
  u16* hn     = (u16*)alloc((size_t)ROWS*DIM*2);
  u16* qkvB   = (u16*)alloc((size_t)ROWS*QKV_LD*2);
  u16* vTb    = (u16*)alloc((size_t)ROWS*DIM*2);
  u16* oB     = (u16*)alloc((size_t)ROWS*DIM*2);
  u16* hB     = (u16*)alloc((size_t)ROWS*DIM*2);
  u16* ffB    = (u16*)alloc((size_t)ROWS*FFD*2);
  float* igF  = (float*)alloc((size_t)ROWS*1024*4);
  u16* qkvT = (u16*)alloc((size_t)NLAYER*1536*DIM*2);
  u16* owT  = (u16*)alloc((size_t)NLAYER*DIM*DIM*2);
  u16* igT  = (u16*)alloc((size_t)NLAYER*1024*DIM*2);
  u16* f1T  = (u16*)alloc((size_t)NLAYER*DIM*FFD*2);
  u16* f2T  = (u16*)alloc((size_t)NLAYER*DIM*FFD*2);
  u16* outT = (u16*)alloc((size_t)VOCAB*DIM*2);
  float* qkvb = (float*)alloc((size_t)NLAYER*1536*4);
  float* igb  = (float*)alloc((size_t)NLAYER*1024*4);

  dim3 tb(32,8);
  transpose_w<<<dim3(DIM/32, DIM/32, NLAYER), tb, 0, stream>>>(qw, qkvT, DIM, DIM, (size_t)1536*DIM, 0);
  transpose_w<<<dim3(DIM/32, DIM/32, NLAYER), tb, 0, stream>>>(kw, qkvT, DIM, DIM, (size_t)1536*DIM, 512);
  transpose_w<<<dim3(DIM/32, DIM/32, NLAYER), tb, 0, stream>>>(vw, qkvT, DIM, DIM, (size_t)1536*DIM, 1024);
  transpose_w<<<dim3(DIM/32, DIM/32, NLAYER), tb, 0, stream>>>(ow, owT, DIM, DIM, (size_t)DIM*DIM, 0);
  transpose_w<<<dim3(DIM/32, DIM/32, NLAYER), tb, 0, stream>>>(iw, igT, DIM, DIM, (size_t)1024*DIM, 0);
  transpose_w<<<dim3(DIM/32, DIM/32, NLAYER), tb, 0, stream>>>(gw, igT, DIM, DIM, (size_t)1024*DIM, 512);
  transpose_w<<<dim3(FFD/32, DIM/32, NLAYER), tb, 0, stream>>>(f1w, f1T, DIM, FFD, (size_t)DIM*FFD, 0);
  transpose_w<<<dim3(DIM/32, FFD/32, NLAYER), tb, 0, stream>>>(f2w, f2T, FFD, DIM, (size_t)DIM*FFD, 0);
  transpose_w<<<dim3(VOCAB/32, DIM/32, 1),    tb, 0, stream>>>(outw, outT, DIM, VOCAB, 0, 0);
  concat3_k<<<NLAYER*1536/256, 256, 0, stream>>>(qb, kb, vb, qkvb);
  concat2_k<<<NLAYER*1024/256, 256, 0, stream>>>(ib, gb, igb);

  embed_k<<<ROWS*DIM/4/256, 256, 0, stream>>>(x, tok_emb, pos_emb, h);

  constexpr size_t SM_MID = 2*(128+128)*32*2;   // 32 KiB
  constexpr size_t SM_ROW = 2*(64+128)*32*2;    // 24 KiB
  constexpr size_t SM_BIG = 2*(256+256)*64*2;   // 128 KiB

  for (int l=0;l<NLAYER;l++){
    ln_k<<<ROWS/4, 256, 0, stream>>>(h, n1w + l*DIM, n1b + l*DIM, hn);
    gemm_p<128,128,32,2,2,1><<<dim3(ROWS/128, 1536/128), 256, SM_MID, stream>>>(
        hn, qkvT + (size_t)l*1536*DIM, qkvb + l*1536, nullptr, nullptr, qkvB, ROWS, 1536, DIM);
    vtrans_k<<<dim3(SEQ/32, HD/32, BATCH*NH), tb, 0, stream>>>(qkvB, vTb);
    attn_k<<<dim3(SEQ/64, NH, BATCH), 256, 0, stream>>>(qkvB, vTb, qphase + l*NH, oB);
    gemm_p<64,128,32,1,4,4><<<dim3(ROWS/64, DIM/128), 256, SM_ROW, stream>>>(
        oB, owT + (size_t)l*DIM*DIM, ob + l*DIM, sp_phase + l*DIM, h, nullptr, ROWS, DIM, DIM);
    ln_k<<<ROWS/4, 256, 0, stream>>>(h, n2w + l*DIM, n2b + l*DIM, hn);
    gemm_p<128,128,32,2,2,3><<<dim3(ROWS/128, FFD/128), 256, SM_MID, stream>>>(
        hn, f1T + (size_t)l*DIM*FFD, f1b + l*FFD, nullptr, nullptr, ffB, ROWS, FFD, DIM);
    gemm_p<64,128,32,1,4,6><<<dim3(ROWS/64, DIM/128), 256, SM_ROW, stream>>>(
        ffB, f2T + (size_t)l*DIM*FFD, f2b + l*DIM, nullptr, h, hB, ROWS, DIM, FFD);
    gemm_p<128,128,32,2,2,0><<<dim3(ROWS/128, 1024/128), 256, SM_MID, stream>>>(
        hB, igT + (size_t)l*1024*DIM, igb + l*1024, nullptr, igF, nullptr, ROWS, 1024, DIM);
    gate_k<<<ROWS*DIM/4/256, 256, 0, stream>>>(h, igF);
  }
  ln_k<<<ROWS/4, 256, 0, stream>>>(h, nw, nb, hn);
  gemm_p<256,256,64,2,4,0><<<dim3(ROWS/256, VOCAB/256), 512, SM_BIG, stream>>>(
      hn, outT, outb, nullptr, out, nullptr, ROWS, VOCAB, DIM);
}